// Round 16
// baseline (65.515 us; speedup 1.0000x reference)
//
#include <hip/hip_runtime.h>
#include <math.h>

typedef unsigned long long ull;

#define TT 64
#define NN 32
#define CC 128
#define DD 64

__device__ __forceinline__ float rdlane(float x, int l) {
    return __builtin_bit_cast(float,
        __builtin_amdgcn_readlane(__builtin_bit_cast(int, x), l));
}
__device__ __forceinline__ unsigned rdlaneu(unsigned x, int l) {
    return (unsigned)__builtin_amdgcn_readlane((int)x, l);
}
__device__ __forceinline__ float bit2f(unsigned m, int j) {
    // 1.0f if bit j set else 0.0f (validated rounds 8-13)
    return __builtin_bit_cast(float, (0u - ((m >> j) & 1u)) & 0x3f800000u);
}

// ---------------------------------------------------------------------------
// Kernel 1a: one wave per (n,c). lane = jeffress dim d. (r13 verbatim)
// ---------------------------------------------------------------------------
__global__ __launch_bounds__(256) void k1a_jeffress(
    const float* __restrict__ x,                 // (T,N,2,C)
    ull* __restrict__ simask)                    // (N*C)
{
#pragma clang fp contract(off)
    const int lane = threadIdx.x & 63;
    const int wid  = (blockIdx.x << 2) + (threadIdx.x >> 6);  // n*C + c
    const int n = wid >> 7;
    const int c = wid & 127;

    const float x0 = x[((lane * NN + n) * 2 + 0) * CC + c];
    const float x1 = x[((lane * NN + n) * 2 + 1) * CC + c];
    const ull m0 = __ballot(x0 > 0.5f) << lane;          // bit t = x0[t-lane]
    const ull m1 = __ballot(x1 > 0.5f) << (63 - lane);   // bit t = x1[t-63+lane]
    const unsigned m0lo = (unsigned)m0, m0hi = (unsigned)(m0 >> 32);
    const unsigned m1lo = (unsigned)m1, m1hi = (unsigned)(m1 >> 32);

    int ad = lane - (DD / 2);
    if (ad < 0) ad = -ad;
    if (ad == 0) ad = 1;                         // center clamp
    const float kint = 1.0f / (1.0f - expf(-(float)ad * 0.5f));

    const float R = 0.05f;                       // RN(1/20)
    float vj = 0.f;
    unsigned rlo = 0u, rhi = 0u;                 // spike row t (on lane t)

    // t = 0..12: spike provably impossible (max vj = 2(1-0.95^13) < 0.974)
#pragma unroll
    for (int t = 0; t < 13; ++t) {
        const unsigned b0 = (m0lo >> t) & 1u;
        const unsigned b1 = (m1lo >> t) & 1u;
        const float u = (float)(b0 + b1);
        const float num = u - vj;
        const float q0  = num * R;
        vj = vj + fmaf(fmaf(-20.0f, q0, num), R, q0);
    }

    // t = 13..63: full LIF + ballot capture
#pragma unroll
    for (int t = 13; t < TT; ++t) {
        const unsigned b0 = (t < 32) ? ((m0lo >> t) & 1u) : ((m0hi >> (t - 32)) & 1u);
        const unsigned b1 = (t < 32) ? ((m1lo >> t) & 1u) : ((m1hi >> (t - 32)) & 1u);
        const float u = (float)(b0 + b1);

        const float num = u - vj;
        const float q0  = num * R;
        const float q   = fmaf(fmaf(-20.0f, q0, num), R, q0);
        vj = vj + q;

        const bool sp = vj >= 1.0f;
        const ull m = __ballot(sp);
        vj = sp ? 0.0f : vj;
        if (t == lane) { rlo = (unsigned)m; rhi = (unsigned)(m >> 32); }
    }

    // zc[t] on lane t: dot(spike row, kint) — exact (each product is 0 or kd)
    float zc = 0.f;
#pragma unroll
    for (int d = 0; d < 64; ++d) {
        const float kd = rdlane(kint, d);
        const unsigned bit = (d < 32) ? ((rlo >> d) & 1u) : ((rhi >> (d - 32)) & 1u);
        zc = fmaf((float)bit, kd, zc);
    }

    // lane-redundant serial integrator IF (zc == 0 for t < 13)
    float vi = 0.f, sreg = 0.f;
#pragma unroll
    for (int t = 13; t < TT; ++t) {
        vi += rdlane(zc, t);
        const bool sp = vi >= 1.0f;
        const float siF = sp ? 1.0f : 0.0f;
        vi = sp ? 0.0f : vi;
        if (t == lane) sreg = siF;
    }
    const ull mm = __ballot(sreg > 0.5f);
    if (lane == 0) simask[wid] = mm;
}

// ---------------------------------------------------------------------------
// Kernel B1: square model, 16 lanes per cell (r13 verbatim).
// ---------------------------------------------------------------------------
__global__ __launch_bounds__(256) void kB1_square(
    const ull* __restrict__ simask,              // (N*C)
    const float* __restrict__ w1,  const float* __restrict__ b1,
    const float* __restrict__ w2,  const float* __restrict__ b2,
    float* __restrict__ fsbuf)                   // (N*C, T)
{
#pragma clang fp contract(off)
    __shared__ float fsl[16][TT + 1];
    const int tid = threadIdx.x;
    const int g   = tid & 15;                    // lane-in-group = k (0..9 live)
    const int cib = tid >> 4;                    // cell-in-block 0..15
    const int cell = (blockIdx.x << 4) + cib;    // n*C + c

    const ull mm = simask[cell];
    const unsigned mlo = (unsigned)mm, mhi = (unsigned)(mm >> 32);

    const int k = (g < 10) ? g : 0;
    const float W1k = w1[k], B1k = b1[k];
    const float W2k = (g < 10) ? w2[k] : 0.0f;   // dead lanes contribute 0
    const float B2  = b2[0];

    float f1 = 0.f, v1 = 0.f, f2 = 0.f, v2 = 0.f, fs = 0.f;

#pragma unroll
    for (int t = 0; t < TT; ++t) {
        const float si = (float)((t < 32) ? ((mlo >> t) & 1u)
                                          : ((mhi >> (t - 32)) & 1u));
        f1 = f1 * 0.5f + si;

        v1 = v1 + (f1 * W1k + B1k);
        const bool s1b = v1 >= 1.0f;
        const float s1 = s1b ? 1.0f : 0.0f;
        v1 = s1b ? 0.0f : v1;

        f2 = f2 * 0.5f + s1;
        float acc = f2 * W2k;
        acc += __shfl_xor(acc, 1);
        acc += __shfl_xor(acc, 2);
        acc += __shfl_xor(acc, 4);
        acc += __shfl_xor(acc, 8);

        v2 = v2 + (acc + B2);
        const bool s2b = v2 >= 1.0f;
        const float s2 = s2b ? 1.0f : 0.0f;
        v2 = s2b ? 0.0f : v2;

        fs = fs * 0.5f + s2;
        fsl[cib][t] = fs;                        // all 16 lanes, same value
    }
    __syncthreads();

    float* dst = fsbuf + (blockIdx.x << 10);
#pragma unroll
    for (int i = tid; i < 16 * TT; i += 256)
        dst[i] = fsl[i >> 6][i & 63];
}

// ---------------------------------------------------------------------------
// Kernel B2 (v16): one wave per n. Four short-chain passes:
//  pass 1: vs + q0 chain -> per-step ballot masks (lane t holds mask of t)
//  pass 2: g1 recon (full 32-wide, r8-validated) + row-k dot off-chain
//          -> part[t][k] in LDS (conflict-free; upper half = broadcast read)
//  pass 3: q1 chain (reads LDS parts) -> per-step sp1 masks
//  pass 4: r9-validated g2/pv/q2 post-loop
// All FP ops/orders from bit-exact-validated rounds (v13 ≡ by commutativity).
// ---------------------------------------------------------------------------
__global__ __launch_bounds__(64) void kB2_v16(
    const float* __restrict__ fsbuf,             // (N*C, T)
    const float* __restrict__ sw0, const float* __restrict__ sb0,
    const float* __restrict__ sw1, const float* __restrict__ sb1,
    const float* __restrict__ sw2, const float* __restrict__ sb2,
    float* __restrict__ out)                     // (T,N,1)
{
#pragma clang fp contract(off)
    __shared__ float ldsp[TT * 32];              // part[t][k], 8 KB
    const int n = blockIdx.x;
    const int tid = threadIdx.x;                 // 0..63 ; phase-2 t = tid
    const int k = tid & 31;

    // ---- phase 2: lane t sums fs[t] over the 128 cells (r4/r13 order) ----
    const float* base = fsbuf + n * (CC * TT);
    float a0 = 0.f, a1 = 0.f, a2 = 0.f, a3 = 0.f;
#pragma unroll
    for (int c = 0; c < CC; c += 4) {
        a0 += base[(c + 0) * TT + tid];
        a1 += base[(c + 1) * TT + tid];
        a2 += base[(c + 2) * TT + tid];
        a3 += base[(c + 3) * TT + tid];
    }
    const float sums = (a0 + a1) + (a2 + a3);

    // ---- pass 1: vs + q0 chain, capture q0-spike mask per step ----
    const float SW0 = sw0[k], SB0 = sb0[k];
    float vs = 0.f, q0v = 0.f;
    unsigned my_m = 0u;                          // lane t: sp0 mask of step t
#pragma unroll 8
    for (int t = 0; t < TT; ++t) {
        const float p = rdlane(sums, t);
        vs += p;
        const bool spv = vs >= 1.0f;
        vs = spv ? 0.0f : vs;
        const float s = spv ? 1.0f : 0.0f;

        q0v = q0v + fmaf(s, SW0, SB0);           // exact: s in {0,1}
        const bool sp0 = q0v >= 1.0f;
        q0v = sp0 ? 0.0f : q0v;

        const unsigned m = (unsigned)__ballot(sp0);
        if (t == tid) my_m = m;
    }

    // ---- pass 2: full-local g1 + row-k dot (no cross-lane FP) ----
    {
        float SW1A[16], SW1B[16];
#pragma unroll
        for (int j = 0; j < 16; ++j) {
            SW1A[j] = sw1[k * 32 + j];
            SW1B[j] = sw1[k * 32 + 16 + j];
        }
        float g1A[16], g1B[16];
#pragma unroll
        for (int j = 0; j < 16; ++j) { g1A[j] = 0.f; g1B[j] = 0.f; }

#pragma unroll 4
        for (int t = 0; t < TT; ++t) {
            const unsigned mt = rdlaneu(my_m, t);    // uniform

#pragma unroll
            for (int j = 0; j < 16; ++j) {
                g1A[j] = fmaf(g1A[j], 0.5f, bit2f(mt, j));
                g1B[j] = fmaf(g1B[j], 0.5f, bit2f(mt, 16 + j));
            }

            // partA + partB (r8-validated association; == v13 by commutativity)
            float b0 = 0.f, b1v = 0.f, b2a = 0.f, b3 = 0.f;
#pragma unroll
            for (int j = 0; j < 16; j += 4) {
                b0  += SW1A[j + 0] * g1A[j + 0];
                b1v += SW1A[j + 1] * g1A[j + 1];
                b2a += SW1A[j + 2] * g1A[j + 2];
                b3  += SW1A[j + 3] * g1A[j + 3];
            }
            const float partA = (b0 + b1v) + (b2a + b3);
            float c0 = 0.f, c1 = 0.f, c2 = 0.f, c3 = 0.f;
#pragma unroll
            for (int j = 0; j < 16; j += 4) {
                c0 += SW1B[j + 0] * g1B[j + 0];
                c1 += SW1B[j + 1] * g1B[j + 1];
                c2 += SW1B[j + 2] * g1B[j + 2];
                c3 += SW1B[j + 3] * g1B[j + 3];
            }
            const float partB = (c0 + c1) + (c2 + c3);
            const float part = partA + partB;

            if (tid < 32) ldsp[t * 32 + k] = part;   // lanes>=32 duplicate
        }
    }

    // ---- pass 3: q1 chain reading LDS parts; capture sp1 masks ----
    const float SB1 = sb1[k];
    float q1 = 0.f;
    unsigned my_m2 = 0u;                         // lane t: sp1 mask of step t
#pragma unroll 4
    for (int t = 0; t < TT; ++t) {
        const float part = ldsp[t * 32 + k];     // conflict-free / broadcast
        q1 = q1 + (part + SB1);
        const bool sp1 = q1 >= 1.0f;
        q1 = sp1 ? 0.0f : q1;

        const unsigned m2 = (unsigned)__ballot(sp1);
        if (t == tid) my_m2 = m2;
    }

    // ---- pass 4: g2 / pv / q2 (r9-validated post-loop) ----
    const float SB2 = sb2[0];
    float SW2A[16], SW2B[16];
#pragma unroll
    for (int j = 0; j < 16; ++j) {
        SW2A[j] = sw2[j];
        SW2B[j] = sw2[16 + j];
    }
    float g2A[16], g2B[16];
#pragma unroll
    for (int j = 0; j < 16; ++j) { g2A[j] = 0.f; g2B[j] = 0.f; }
    float q2 = 0.f;

#pragma unroll 4
    for (int t = 0; t < TT; ++t) {
        const unsigned m2t = rdlaneu(my_m2, t);  // uniform

#pragma unroll
        for (int j = 0; j < 16; ++j) {
            g2A[j] = fmaf(g2A[j], 0.5f, bit2f(m2t, j));
            g2B[j] = fmaf(g2B[j], 0.5f, bit2f(m2t, 16 + j));
        }

        const float t0 = (g2A[0]  * SW2A[0]  + g2A[1]  * SW2A[1])
                       + (g2A[2]  * SW2A[2]  + g2A[3]  * SW2A[3]);
        const float t1 = (g2A[4]  * SW2A[4]  + g2A[5]  * SW2A[5])
                       + (g2A[6]  * SW2A[6]  + g2A[7]  * SW2A[7]);
        const float t2 = (g2A[8]  * SW2A[8]  + g2A[9]  * SW2A[9])
                       + (g2A[10] * SW2A[10] + g2A[11] * SW2A[11]);
        const float t3 = (g2A[12] * SW2A[12] + g2A[13] * SW2A[13])
                       + (g2A[14] * SW2A[14] + g2A[15] * SW2A[15]);
        const float RA = (t0 + t1) + (t2 + t3);
        const float u0 = (g2B[0]  * SW2B[0]  + g2B[1]  * SW2B[1])
                       + (g2B[2]  * SW2B[2]  + g2B[3]  * SW2B[3]);
        const float u1 = (g2B[4]  * SW2B[4]  + g2B[5]  * SW2B[5])
                       + (g2B[6]  * SW2B[6]  + g2B[7]  * SW2B[7]);
        const float u2 = (g2B[8]  * SW2B[8]  + g2B[9]  * SW2B[9])
                       + (g2B[10] * SW2B[10] + g2B[11] * SW2B[11]);
        const float u3 = (g2B[12] * SW2B[12] + g2B[13] * SW2B[13])
                       + (g2B[14] * SW2B[14] + g2B[15] * SW2B[15]);
        const float RB = (u0 + u1) + (u2 + u3);

        q2 += (RB + RA) + SB2;
        if (tid == 0) out[t * NN + n] = q2;
    }
}

// ---------------------------------------------------------------------------
extern "C" void kernel_launch(void* const* d_in, const int* in_sizes, int n_in,
                              void* d_out, int out_size, void* d_ws, size_t ws_size,
                              hipStream_t stream)
{
    const float* x   = (const float*)d_in[0];
    const float* w1  = (const float*)d_in[1];
    const float* b1  = (const float*)d_in[2];
    const float* w2  = (const float*)d_in[3];
    const float* b2  = (const float*)d_in[4];
    const float* sw0 = (const float*)d_in[5];
    const float* sb0 = (const float*)d_in[6];
    const float* sw1 = (const float*)d_in[7];
    const float* sb1 = (const float*)d_in[8];
    const float* sw2 = (const float*)d_in[9];
    const float* sb2 = (const float*)d_in[10];
    float* out = (float*)d_out;

    ull*   simask = (ull*)d_ws;                        // 4096 * 8 B
    float* fsbuf  = (float*)((char*)d_ws + (1 << 20)); // 4096*64*4 B = 1 MiB

    hipLaunchKernelGGL(k1a_jeffress, dim3((NN * CC) / 4), dim3(256), 0, stream,
                       x, simask);
    hipLaunchKernelGGL(kB1_square, dim3((NN * CC) / 16), dim3(256), 0, stream,
                       simask, w1, b1, w2, b2, fsbuf);
    hipLaunchKernelGGL(kB2_v16, dim3(NN), dim3(64), 0, stream,
                       fsbuf, sw0, sb0, sw1, sb1, sw2, sb2, out);
}

// Round 17
// 35.752 us; speedup vs baseline: 1.8325x; 1.8325x over previous
//
#include <hip/hip_runtime.h>
#include <math.h>

typedef unsigned long long ull;

#define TT 64
#define NN 32
#define CC 128
#define DD 64

// ---------------------------------------------------------------------------
// DPP helpers (VALU-pipe cross-lane)
// ---------------------------------------------------------------------------
#define DPPADD(x, ctrl, rm)                                                   \
    x += __builtin_bit_cast(float, __builtin_amdgcn_update_dpp(               \
             0, __builtin_bit_cast(int, x), ctrl, rm, 0xf, false))

__device__ __forceinline__ float wave_reduce63(float x) {
    DPPADD(x, 0x111, 0xf);  // row_shr:1
    DPPADD(x, 0x112, 0xf);  // row_shr:2
    DPPADD(x, 0x114, 0xf);  // row_shr:4
    DPPADD(x, 0x118, 0xf);  // row_shr:8
    DPPADD(x, 0x142, 0xa);  // row_bcast:15
    DPPADD(x, 0x143, 0xc);  // row_bcast:31 -> lane63 = total
    return x;
}

__device__ __forceinline__ float rdlane(float x, int l) {
    return __builtin_bit_cast(float,
        __builtin_amdgcn_readlane(__builtin_bit_cast(int, x), l));
}
__device__ __forceinline__ float bit2f(unsigned m, int j) {
    // 1.0f if bit j set else 0.0f (validated rounds 8-13)
    return __builtin_bit_cast(float, (0u - ((m >> j) & 1u)) & 0x3f800000u);
}

// ---------------------------------------------------------------------------
// Kernel 1a: one wave per (n,c). lane = jeffress dim d. (r13 verbatim)
// ---------------------------------------------------------------------------
__global__ __launch_bounds__(256) void k1a_jeffress(
    const float* __restrict__ x,                 // (T,N,2,C)
    ull* __restrict__ simask)                    // (N*C)
{
#pragma clang fp contract(off)
    const int lane = threadIdx.x & 63;
    const int wid  = (blockIdx.x << 2) + (threadIdx.x >> 6);  // n*C + c
    const int n = wid >> 7;
    const int c = wid & 127;

    const float x0 = x[((lane * NN + n) * 2 + 0) * CC + c];
    const float x1 = x[((lane * NN + n) * 2 + 1) * CC + c];
    const ull m0 = __ballot(x0 > 0.5f) << lane;          // bit t = x0[t-lane]
    const ull m1 = __ballot(x1 > 0.5f) << (63 - lane);   // bit t = x1[t-63+lane]
    const unsigned m0lo = (unsigned)m0, m0hi = (unsigned)(m0 >> 32);
    const unsigned m1lo = (unsigned)m1, m1hi = (unsigned)(m1 >> 32);

    int ad = lane - (DD / 2);
    if (ad < 0) ad = -ad;
    if (ad == 0) ad = 1;                         // center clamp
    const float kint = 1.0f / (1.0f - expf(-(float)ad * 0.5f));

    const float R = 0.05f;                       // RN(1/20)
    float vj = 0.f;
    unsigned rlo = 0u, rhi = 0u;                 // spike row t (on lane t)

    // t = 0..12: spike provably impossible (max vj = 2(1-0.95^13) < 0.974)
#pragma unroll
    for (int t = 0; t < 13; ++t) {
        const unsigned b0 = (m0lo >> t) & 1u;
        const unsigned b1 = (m1lo >> t) & 1u;
        const float u = (float)(b0 + b1);
        const float num = u - vj;
        const float q0  = num * R;
        vj = vj + fmaf(fmaf(-20.0f, q0, num), R, q0);
    }

    // t = 13..63: full LIF + ballot capture
#pragma unroll
    for (int t = 13; t < TT; ++t) {
        const unsigned b0 = (t < 32) ? ((m0lo >> t) & 1u) : ((m0hi >> (t - 32)) & 1u);
        const unsigned b1 = (t < 32) ? ((m1lo >> t) & 1u) : ((m1hi >> (t - 32)) & 1u);
        const float u = (float)(b0 + b1);

        const float num = u - vj;
        const float q0  = num * R;
        const float q   = fmaf(fmaf(-20.0f, q0, num), R, q0);
        vj = vj + q;

        const bool sp = vj >= 1.0f;
        const ull m = __ballot(sp);
        vj = sp ? 0.0f : vj;
        if (t == lane) { rlo = (unsigned)m; rhi = (unsigned)(m >> 32); }
    }

    // zc[t] on lane t: dot(spike row, kint) — exact (each product is 0 or kd)
    float zc = 0.f;
#pragma unroll
    for (int d = 0; d < 64; ++d) {
        const float kd = rdlane(kint, d);
        const unsigned bit = (d < 32) ? ((rlo >> d) & 1u) : ((rhi >> (d - 32)) & 1u);
        zc = fmaf((float)bit, kd, zc);
    }

    // lane-redundant serial integrator IF (zc == 0 for t < 13)
    float vi = 0.f, sreg = 0.f;
#pragma unroll
    for (int t = 13; t < TT; ++t) {
        vi += rdlane(zc, t);
        const bool sp = vi >= 1.0f;
        const float siF = sp ? 1.0f : 0.0f;
        vi = sp ? 0.0f : vi;
        if (t == lane) sreg = siF;
    }
    const ull mm = __ballot(sreg > 0.5f);
    if (lane == 0) simask[wid] = mm;
}

// ---------------------------------------------------------------------------
// Kernel B1: square model, 16 lanes per cell (r13 verbatim).
// ---------------------------------------------------------------------------
__global__ __launch_bounds__(256) void kB1_square(
    const ull* __restrict__ simask,              // (N*C)
    const float* __restrict__ w1,  const float* __restrict__ b1,
    const float* __restrict__ w2,  const float* __restrict__ b2,
    float* __restrict__ fsbuf)                   // (N*C, T)
{
#pragma clang fp contract(off)
    __shared__ float fsl[16][TT + 1];
    const int tid = threadIdx.x;
    const int g   = tid & 15;                    // lane-in-group = k (0..9 live)
    const int cib = tid >> 4;                    // cell-in-block 0..15
    const int cell = (blockIdx.x << 4) + cib;    // n*C + c

    const ull mm = simask[cell];
    const unsigned mlo = (unsigned)mm, mhi = (unsigned)(mm >> 32);

    const int k = (g < 10) ? g : 0;
    const float W1k = w1[k], B1k = b1[k];
    const float W2k = (g < 10) ? w2[k] : 0.0f;   // dead lanes contribute 0
    const float B2  = b2[0];

    float f1 = 0.f, v1 = 0.f, f2 = 0.f, v2 = 0.f, fs = 0.f;

#pragma unroll
    for (int t = 0; t < TT; ++t) {
        const float si = (float)((t < 32) ? ((mlo >> t) & 1u)
                                          : ((mhi >> (t - 32)) & 1u));
        f1 = f1 * 0.5f + si;

        v1 = v1 + (f1 * W1k + B1k);
        const bool s1b = v1 >= 1.0f;
        const float s1 = s1b ? 1.0f : 0.0f;
        v1 = s1b ? 0.0f : v1;

        f2 = f2 * 0.5f + s1;
        float acc = f2 * W2k;
        acc += __shfl_xor(acc, 1);
        acc += __shfl_xor(acc, 2);
        acc += __shfl_xor(acc, 4);
        acc += __shfl_xor(acc, 8);

        v2 = v2 + (acc + B2);
        const bool s2b = v2 >= 1.0f;
        const float s2 = s2b ? 1.0f : 0.0f;
        v2 = s2b ? 0.0f : v2;

        fs = fs * 0.5f + s2;
        fsl[cib][t] = fs;                        // all 16 lanes, same value
    }
    __syncthreads();

    float* dst = fsbuf + (blockIdx.x << 10);
#pragma unroll
    for (int i = tid; i < 16 * TT; i += 256)
        dst[i] = fsl[i >> 6][i & 63];
}

// ---------------------------------------------------------------------------
// Kernel B2 (v17): v13 + exact quiet-step deferral.
//  - If vs doesn't spike AND all sb0 == 0 (uniform runtime flag), q0 is
//    exactly unchanged and m == 0 without computing the ballot.
//  - During a run of L such steps g1[j] halves exactly each step; defer as
//    a counter, catch up with one exact *2^-L before the next recon.
// Everything else (q1/ptot/g2/pvs/q2) is v13 verbatim.
// ---------------------------------------------------------------------------
__global__ __launch_bounds__(64) void kB2_v17(
    const float* __restrict__ fsbuf,             // (N*C, T)
    const float* __restrict__ sw0, const float* __restrict__ sb0,
    const float* __restrict__ sw1, const float* __restrict__ sb1,
    const float* __restrict__ sw2, const float* __restrict__ sb2,
    float* __restrict__ out)                     // (T,N,1)
{
#pragma clang fp contract(off)
    const int n = blockIdx.x;
    const int tid = threadIdx.x;                 // 0..63 ; phase-2 t = tid
    const int k = tid & 31;
    const int h = tid >> 5;

    // ---- phase 2: lane t sums fs[t] over the 128 cells (r4/r13 order) ----
    const float* base = fsbuf + n * (CC * TT);
    float a0 = 0.f, a1 = 0.f, a2 = 0.f, a3 = 0.f;
#pragma unroll
    for (int c = 0; c < CC; c += 4) {
        a0 += base[(c + 0) * TT + tid];
        a1 += base[(c + 1) * TT + tid];
        a2 += base[(c + 2) * TT + tid];
        a3 += base[(c + 3) * TT + tid];
    }
    const float sums = (a0 + a1) + (a2 + a3);

    // ---- weights (r4 layout: half-row per lane) ----
    const float SW0 = sw0[k], SB0 = sb0[k], SB1 = sb1[k];
    float SW1[16];
#pragma unroll
    for (int j = 0; j < 16; ++j) SW1[j] = sw1[k * 32 + h * 16 + j];
    const float SW2j = (tid < 32) ? sw2[k] : 0.0f;
    const float SB2 = sb2[0];

    // uniform flag: every lane's SB0 is +-0 -> q0 exactly invariant on s==0
    const bool zb0 = (__ballot(SB0 == 0.0f) == ~0ull);

    float vs = 0.f, q0 = 0.f, q1 = 0.f, g2 = 0.f, q2 = 0.f;
    float g1loc[16];
#pragma unroll
    for (int j = 0; j < 16; ++j) g1loc[j] = 0.f;
    float ptot = 0.f;                            // carried part total
    float pvs  = 0.f;                            // carried reduced pv
    int   L    = 0;                              // pending exact g1 halvings

#pragma unroll 4
    for (int t = 0; t < TT; ++t) {
        // vs recurrence (uniform across lanes)
        const float p = rdlane(sums, t);
        vs += p;
        const bool spv = vs >= 1.0f;
        vs = spv ? 0.0f : vs;
        const float s = spv ? 1.0f : 0.0f;

        unsigned m;
        if (spv || !zb0) {
            // q0 recurrence: fmaf == (s*SW0)+SB0 exactly (s in {0,1})
            q0 = q0 + fmaf(s, SW0, SB0);
            const bool sp0 = q0 >= 1.0f;
            q0 = sp0 ? 0.0f : q0;
            m = (unsigned)__ballot(sp0);         // uniform; bits = per-k
        } else {
            // q0 + 0 == q0 exactly; post-reset q0 < 1 -> no spikes
            m = 0u;
        }

        if (m != 0) {
            // catch-up: g1 *= 2^-L (exact; g1 entries are 0 or >= 2^-63)
            if (L) {
                const float sc = __builtin_bit_cast(float,
                                     (unsigned)(127 - L) << 23);
#pragma unroll
                for (int j = 0; j < 16; ++j) g1loc[j] *= sc;
                L = 0;
            }
            // g1 recon (fma exact: *0.5) — v13 verbatim
#pragma unroll
            for (int j = 0; j < 16; ++j)
                g1loc[j] = fmaf(g1loc[j], 0.5f, bit2f(m, h * 16 + j));

            // dot over my half (r4 order) + half-combine — v13 verbatim
            float b0 = 0.f, b1v = 0.f, b2a = 0.f, b3 = 0.f;
#pragma unroll
            for (int j = 0; j < 16; j += 4) {
                b0  += SW1[j + 0] * g1loc[j + 0];
                b1v += SW1[j + 1] * g1loc[j + 1];
                b2a += SW1[j + 2] * g1loc[j + 2];
                b3  += SW1[j + 3] * g1loc[j + 3];
            }
            float part = (b0 + b1v) + (b2a + b3);
            part += __shfl_xor(part, 32);
            ptot = part;
        } else {
            // all g1 halved exactly -> dot halves exactly
            ++L;
            ptot = 0.5f * ptot;
        }

        // q1 recurrence — v13 verbatim
        q1 = q1 + (ptot + SB1);
        const bool sp1 = q1 >= 1.0f;
        const float s1 = sp1 ? 1.0f : 0.0f;
        q1 = sp1 ? 0.0f : q1;

        const unsigned m2 = (unsigned)__ballot(sp1);  // uniform

        // g2 per-lane scalar: fmaf == g2*0.5 + s1 exactly
        g2 = fmaf(g2, 0.5f, s1);

        if (m2 != 0) {
            float pv = g2 * SW2j;
            pv = wave_reduce63(pv);
            pvs = rdlane(pv, 63);
        } else {
            // all g2 halved exactly -> DPP-reduced sum halves exactly
            pvs = 0.5f * pvs;
        }

        // q2 recurrence — v13 verbatim
        q2 = q2 + (pvs + SB2);
        if (tid == 0) out[t * NN + n] = q2;
    }
}

// ---------------------------------------------------------------------------
extern "C" void kernel_launch(void* const* d_in, const int* in_sizes, int n_in,
                              void* d_out, int out_size, void* d_ws, size_t ws_size,
                              hipStream_t stream)
{
    const float* x   = (const float*)d_in[0];
    const float* w1  = (const float*)d_in[1];
    const float* b1  = (const float*)d_in[2];
    const float* w2  = (const float*)d_in[3];
    const float* b2  = (const float*)d_in[4];
    const float* sw0 = (const float*)d_in[5];
    const float* sb0 = (const float*)d_in[6];
    const float* sw1 = (const float*)d_in[7];
    const float* sb1 = (const float*)d_in[8];
    const float* sw2 = (const float*)d_in[9];
    const float* sb2 = (const float*)d_in[10];
    float* out = (float*)d_out;

    ull*   simask = (ull*)d_ws;                        // 4096 * 8 B
    float* fsbuf  = (float*)((char*)d_ws + (1 << 20)); // 4096*64*4 B = 1 MiB

    hipLaunchKernelGGL(k1a_jeffress, dim3((NN * CC) / 4), dim3(256), 0, stream,
                       x, simask);
    hipLaunchKernelGGL(kB1_square, dim3((NN * CC) / 16), dim3(256), 0, stream,
                       simask, w1, b1, w2, b2, fsbuf);
    hipLaunchKernelGGL(kB2_v17, dim3(NN), dim3(64), 0, stream,
                       fsbuf, sw0, sb0, sw1, sb1, sw2, sb2, out);
}

// Round 18
// 34.506 us; speedup vs baseline: 1.8986x; 1.0361x over previous
//
#include <hip/hip_runtime.h>
#include <math.h>

typedef unsigned long long ull;

#define TT 64
#define NN 32
#define CC 128
#define DD 64

// ---------------------------------------------------------------------------
// DPP helpers (VALU-pipe cross-lane)
// ---------------------------------------------------------------------------
#define DPPADD(x, ctrl, rm)                                                   \
    x += __builtin_bit_cast(float, __builtin_amdgcn_update_dpp(               \
             0, __builtin_bit_cast(int, x), ctrl, rm, 0xf, false))

__device__ __forceinline__ float wave_reduce63(float x) {
    DPPADD(x, 0x111, 0xf);  // row_shr:1
    DPPADD(x, 0x112, 0xf);  // row_shr:2
    DPPADD(x, 0x114, 0xf);  // row_shr:4
    DPPADD(x, 0x118, 0xf);  // row_shr:8
    DPPADD(x, 0x142, 0xa);  // row_bcast:15
    DPPADD(x, 0x143, 0xc);  // row_bcast:31 -> lane63 = total
    return x;
}

__device__ __forceinline__ float rdlane(float x, int l) {
    return __builtin_bit_cast(float,
        __builtin_amdgcn_readlane(__builtin_bit_cast(int, x), l));
}
__device__ __forceinline__ float bit2f(unsigned m, int j) {
    // 1.0f if bit j set else 0.0f (validated rounds 8-17)
    return __builtin_bit_cast(float, (0u - ((m >> j) & 1u)) & 0x3f800000u);
}

// ---------------------------------------------------------------------------
// Kernel AB: 256 blocks x 1024 threads (16 waves = 16 cells; 1 block/CU).
// Phase A (per wave, k1a r13-verbatim): jeffress LIF + integrator -> mask mm.
// Masks hop through LDS (no global round-trip).
// Phase B (threads 0..255, kB1 r13-verbatim): square model, 16 lanes/cell,
// fsl staging + coalesced dump. Idle waves wait at the barriers.
// ---------------------------------------------------------------------------
__global__ __launch_bounds__(1024) void kAB(
    const float* __restrict__ x,                 // (T,N,2,C)
    const float* __restrict__ w1,  const float* __restrict__ b1,
    const float* __restrict__ w2,  const float* __restrict__ b2,
    float* __restrict__ fsbuf)                   // (N*C, T)
{
#pragma clang fp contract(off)
    __shared__ ull   maskLds[16];
    __shared__ float fsl[16][TT + 1];

    const int tid  = threadIdx.x;
    const int lane = tid & 63;
    const int w    = tid >> 6;                   // wave = cell-in-block
    const int wid  = (blockIdx.x << 4) + w;      // n*C + c
    const int n = wid >> 7;
    const int c = wid & 127;

    // ---- phase A: jeffress LIF + integrator (k1a r13 verbatim) ----
    {
        const float x0 = x[((lane * NN + n) * 2 + 0) * CC + c];
        const float x1 = x[((lane * NN + n) * 2 + 1) * CC + c];
        const ull m0 = __ballot(x0 > 0.5f) << lane;          // bit t = x0[t-lane]
        const ull m1 = __ballot(x1 > 0.5f) << (63 - lane);   // bit t = x1[t-63+lane]
        const unsigned m0lo = (unsigned)m0, m0hi = (unsigned)(m0 >> 32);
        const unsigned m1lo = (unsigned)m1, m1hi = (unsigned)(m1 >> 32);

        int ad = lane - (DD / 2);
        if (ad < 0) ad = -ad;
        if (ad == 0) ad = 1;                     // center clamp
        const float kint = 1.0f / (1.0f - expf(-(float)ad * 0.5f));

        const float R = 0.05f;                   // RN(1/20)
        float vj = 0.f;
        unsigned rlo = 0u, rhi = 0u;             // spike row t (on lane t)

        // t = 0..12: spike provably impossible (max vj = 2(1-0.95^13) < 0.974)
#pragma unroll
        for (int t = 0; t < 13; ++t) {
            const unsigned b0 = (m0lo >> t) & 1u;
            const unsigned b1b = (m1lo >> t) & 1u;
            const float u = (float)(b0 + b1b);
            const float num = u - vj;
            const float q0  = num * R;
            vj = vj + fmaf(fmaf(-20.0f, q0, num), R, q0);
        }

        // t = 13..63: full LIF + ballot capture
#pragma unroll
        for (int t = 13; t < TT; ++t) {
            const unsigned b0 = (t < 32) ? ((m0lo >> t) & 1u) : ((m0hi >> (t - 32)) & 1u);
            const unsigned b1b = (t < 32) ? ((m1lo >> t) & 1u) : ((m1hi >> (t - 32)) & 1u);
            const float u = (float)(b0 + b1b);

            const float num = u - vj;
            const float q0  = num * R;
            const float q   = fmaf(fmaf(-20.0f, q0, num), R, q0);
            vj = vj + q;

            const bool sp = vj >= 1.0f;
            const ull m = __ballot(sp);
            vj = sp ? 0.0f : vj;
            if (t == lane) { rlo = (unsigned)m; rhi = (unsigned)(m >> 32); }
        }

        // zc[t] on lane t: dot(spike row, kint) — exact
        float zc = 0.f;
#pragma unroll
        for (int d = 0; d < 64; ++d) {
            const float kd = rdlane(kint, d);
            const unsigned bit = (d < 32) ? ((rlo >> d) & 1u) : ((rhi >> (d - 32)) & 1u);
            zc = fmaf((float)bit, kd, zc);
        }

        // lane-redundant serial integrator IF (zc == 0 for t < 13)
        float vi = 0.f, sreg = 0.f;
#pragma unroll
        for (int t = 13; t < TT; ++t) {
            vi += rdlane(zc, t);
            const bool sp = vi >= 1.0f;
            const float siF = sp ? 1.0f : 0.0f;
            vi = sp ? 0.0f : vi;
            if (t == lane) sreg = siF;
        }
        const ull mm = __ballot(sreg > 0.5f);
        if (lane == 0) maskLds[w] = mm;
    }
    __syncthreads();

    // ---- phase B: square model (kB1 r13 verbatim; threads 0..255) ----
    if (tid < 256) {
        const int g   = tid & 15;                // lane-in-group = k (0..9 live)
        const int cib = tid >> 4;                // cell-in-block 0..15

        const ull mm = maskLds[cib];
        const unsigned mlo = (unsigned)mm, mhi = (unsigned)(mm >> 32);

        const int k = (g < 10) ? g : 0;
        const float W1k = w1[k], B1k = b1[k];
        const float W2k = (g < 10) ? w2[k] : 0.0f;
        const float B2  = b2[0];

        float f1 = 0.f, v1 = 0.f, f2 = 0.f, v2 = 0.f, fs = 0.f;

#pragma unroll
        for (int t = 0; t < TT; ++t) {
            const float si = (float)((t < 32) ? ((mlo >> t) & 1u)
                                              : ((mhi >> (t - 32)) & 1u));
            f1 = f1 * 0.5f + si;

            v1 = v1 + (f1 * W1k + B1k);
            const bool s1b = v1 >= 1.0f;
            const float s1 = s1b ? 1.0f : 0.0f;
            v1 = s1b ? 0.0f : v1;

            f2 = f2 * 0.5f + s1;
            float acc = f2 * W2k;
            acc += __shfl_xor(acc, 1);
            acc += __shfl_xor(acc, 2);
            acc += __shfl_xor(acc, 4);
            acc += __shfl_xor(acc, 8);

            v2 = v2 + (acc + B2);
            const bool s2b = v2 >= 1.0f;
            const float s2 = s2b ? 1.0f : 0.0f;
            v2 = s2b ? 0.0f : v2;

            fs = fs * 0.5f + s2;
            fsl[cib][t] = fs;                    // all 16 lanes, same value
        }
    }
    __syncthreads();

    if (tid < 256) {
        float* dst = fsbuf + (blockIdx.x << 10);
#pragma unroll
        for (int i = tid; i < 16 * TT; i += 256)
            dst[i] = fsl[i >> 6][i & 63];
    }
}

// ---------------------------------------------------------------------------
// Kernel B2 (v17 verbatim): v13 + exact quiet-step deferral.
// ---------------------------------------------------------------------------
__global__ __launch_bounds__(64) void kB2_v17(
    const float* __restrict__ fsbuf,             // (N*C, T)
    const float* __restrict__ sw0, const float* __restrict__ sb0,
    const float* __restrict__ sw1, const float* __restrict__ sb1,
    const float* __restrict__ sw2, const float* __restrict__ sb2,
    float* __restrict__ out)                     // (T,N,1)
{
#pragma clang fp contract(off)
    const int n = blockIdx.x;
    const int tid = threadIdx.x;                 // 0..63 ; phase-2 t = tid
    const int k = tid & 31;
    const int h = tid >> 5;

    // ---- phase 2: lane t sums fs[t] over the 128 cells (r4/r13 order) ----
    const float* base = fsbuf + n * (CC * TT);
    float a0 = 0.f, a1 = 0.f, a2 = 0.f, a3 = 0.f;
#pragma unroll
    for (int c = 0; c < CC; c += 4) {
        a0 += base[(c + 0) * TT + tid];
        a1 += base[(c + 1) * TT + tid];
        a2 += base[(c + 2) * TT + tid];
        a3 += base[(c + 3) * TT + tid];
    }
    const float sums = (a0 + a1) + (a2 + a3);

    // ---- weights (r4 layout: half-row per lane) ----
    const float SW0 = sw0[k], SB0 = sb0[k], SB1 = sb1[k];
    float SW1[16];
#pragma unroll
    for (int j = 0; j < 16; ++j) SW1[j] = sw1[k * 32 + h * 16 + j];
    const float SW2j = (tid < 32) ? sw2[k] : 0.0f;
    const float SB2 = sb2[0];

    // uniform flag: every lane's SB0 is +-0 -> q0 exactly invariant on s==0
    const bool zb0 = (__ballot(SB0 == 0.0f) == ~0ull);

    float vs = 0.f, q0 = 0.f, q1 = 0.f, g2 = 0.f, q2 = 0.f;
    float g1loc[16];
#pragma unroll
    for (int j = 0; j < 16; ++j) g1loc[j] = 0.f;
    float ptot = 0.f;                            // carried part total
    float pvs  = 0.f;                            // carried reduced pv
    int   L    = 0;                              // pending exact g1 halvings

#pragma unroll 4
    for (int t = 0; t < TT; ++t) {
        // vs recurrence (uniform across lanes)
        const float p = rdlane(sums, t);
        vs += p;
        const bool spv = vs >= 1.0f;
        vs = spv ? 0.0f : vs;
        const float s = spv ? 1.0f : 0.0f;

        unsigned m;
        if (spv || !zb0) {
            // q0 recurrence: fmaf == (s*SW0)+SB0 exactly (s in {0,1})
            q0 = q0 + fmaf(s, SW0, SB0);
            const bool sp0 = q0 >= 1.0f;
            q0 = sp0 ? 0.0f : q0;
            m = (unsigned)__ballot(sp0);         // uniform; bits = per-k
        } else {
            // q0 + 0 == q0 exactly; post-reset q0 < 1 -> no spikes
            m = 0u;
        }

        if (m != 0) {
            // catch-up: g1 *= 2^-L (exact; g1 entries are 0 or >= 2^-63)
            if (L) {
                const float sc = __builtin_bit_cast(float,
                                     (unsigned)(127 - L) << 23);
#pragma unroll
                for (int j = 0; j < 16; ++j) g1loc[j] *= sc;
                L = 0;
            }
            // g1 recon (fma exact: *0.5) — v13 verbatim
#pragma unroll
            for (int j = 0; j < 16; ++j)
                g1loc[j] = fmaf(g1loc[j], 0.5f, bit2f(m, h * 16 + j));

            // dot over my half (r4 order) + half-combine — v13 verbatim
            float b0 = 0.f, b1v = 0.f, b2a = 0.f, b3 = 0.f;
#pragma unroll
            for (int j = 0; j < 16; j += 4) {
                b0  += SW1[j + 0] * g1loc[j + 0];
                b1v += SW1[j + 1] * g1loc[j + 1];
                b2a += SW1[j + 2] * g1loc[j + 2];
                b3  += SW1[j + 3] * g1loc[j + 3];
            }
            float part = (b0 + b1v) + (b2a + b3);
            part += __shfl_xor(part, 32);
            ptot = part;
        } else {
            // all g1 halved exactly -> dot halves exactly
            ++L;
            ptot = 0.5f * ptot;
        }

        // q1 recurrence — v13 verbatim
        q1 = q1 + (ptot + SB1);
        const bool sp1 = q1 >= 1.0f;
        const float s1 = sp1 ? 1.0f : 0.0f;
        q1 = sp1 ? 0.0f : q1;

        const unsigned m2 = (unsigned)__ballot(sp1);  // uniform

        // g2 per-lane scalar: fmaf == g2*0.5 + s1 exactly
        g2 = fmaf(g2, 0.5f, s1);

        if (m2 != 0) {
            float pv = g2 * SW2j;
            pv = wave_reduce63(pv);
            pvs = rdlane(pv, 63);
        } else {
            // all g2 halved exactly -> DPP-reduced sum halves exactly
            pvs = 0.5f * pvs;
        }

        // q2 recurrence — v13 verbatim
        q2 = q2 + (pvs + SB2);
        if (tid == 0) out[t * NN + n] = q2;
    }
}

// ---------------------------------------------------------------------------
extern "C" void kernel_launch(void* const* d_in, const int* in_sizes, int n_in,
                              void* d_out, int out_size, void* d_ws, size_t ws_size,
                              hipStream_t stream)
{
    const float* x   = (const float*)d_in[0];
    const float* w1  = (const float*)d_in[1];
    const float* b1  = (const float*)d_in[2];
    const float* w2  = (const float*)d_in[3];
    const float* b2  = (const float*)d_in[4];
    const float* sw0 = (const float*)d_in[5];
    const float* sb0 = (const float*)d_in[6];
    const float* sw1 = (const float*)d_in[7];
    const float* sb1 = (const float*)d_in[8];
    const float* sw2 = (const float*)d_in[9];
    const float* sb2 = (const float*)d_in[10];
    float* out = (float*)d_out;

    float* fsbuf = (float*)d_ws;                 // 4096*64*4 B = 1 MiB

    hipLaunchKernelGGL(kAB, dim3((NN * CC) / 16), dim3(1024), 0, stream,
                       x, w1, b1, w2, b2, fsbuf);
    hipLaunchKernelGGL(kB2_v17, dim3(NN), dim3(64), 0, stream,
                       fsbuf, sw0, sb0, sw1, sb1, sw2, sb2, out);
}